// Round 15
// baseline (102.518 us; speedup 1.0000x reference)
//
#include <hip/hip_runtime.h>
#include <stdint.h>
#include <stddef.h>

typedef __bf16 bf16_t;
typedef __bf16 bf16x8 __attribute__((ext_vector_type(8)));
typedef float  f32x4  __attribute__((ext_vector_type(4)));

#define NIMG 16
#define CIN  128
#define COUT 128
#define HH   56
#define WW   56
#define HW   (HH * WW)       // 3136
#define CDIM 58              // staged c extent: c = w+1, w = -1..56
#define LSTR 136             // LDS c-stride in bf16: 272B record
#define ROWPAIRS 28
#define NBLK (NIMG * ROWPAIRS)   // 448 blocks, 2 output rows each

// R15: LDS-BW fix. Arithmetic: per block-phase, old partition (8 waves x 4
// ds_read_b128 x 1KB = 32KB) vs 78 cyc of MFMA -> ~5x LDS oversubscription at
// 85 B/cyc/CU; K-loop was LDS-bound (~11.6us/CU), explaining why all staging
// overlap attempts were null. New wave partition ws(2) x wc(2) x tsh(2): each
// wave owns 64 co x 32 cols -> 2 m-reads feed 8 MFMA (4 MFMA per KB read,
// 2x the reuse). Weight frags/phase double to 4, but the 4 waves sharing a wc
// read identical addresses (L1 dedup). Staging: simple sync (not the lever).

// ---------- prologue: W[co][ci][3][3] fp32 -> Wt2 fragment-major bf16 ----------
// 288 recs * 64 lanes = 18432 threads = EXACTLY 72 blocks (overrun raced in R2/R3).
__global__ void wtrans_kernel(const float* __restrict__ w, bf16_t* __restrict__ wt2) {
    int t = blockIdx.x * 256 + threadIdx.x;
    int lane = t & 63, rec = t >> 6;              // rec 0..287
    int l15 = lane & 15, l4 = lane >> 4;
    int cotile = rec & 7, chunk = (rec >> 3) & 3, khkw = rec >> 5;
    int co  = cotile * 16 + l15;
    int ci0 = chunk * 32 + l4 * 8;
    const float* src = w + ((size_t)co * CIN + ci0) * 9 + khkw;
    bf16x8 o;
#pragma unroll
    for (int j = 0; j < 8; ++j) o[j] = (bf16_t)src[(size_t)j * 9];
    *(bf16x8*)(wt2 + (size_t)rec * 512 + (size_t)lane * 8) = o;
}

// ---------- fused conv: block = (n, 2 rows) x 128 co; 512 thr = 8 waves ----------
// wave = tsh*4 + wc*2 + ws: ws = output row, wc = co half (64), tsh = col half (32).
// Phase I in [0,36): half = I/18, khkw = (I%18)>>1, cs = I&1; 8 MFMA (tc 0..3 x tsl 0..1).
// rec = (khkw*4 + half*2+cs)*8 + (wc*4 + tc)  ->  4 contiguous frags per phase.
#define FRAG_OFF(I) ((size_t)((((((I) % 18) >> 1) * 4 + (((I) / 18) * 2 + ((I) & 1))) * 8)) * 512)

// m0 col = tsh*32 + l15 + kw (max 49, never clamps). m1 col = tsh*32+16+l15+kw,
// clamped to <=57 (only tsh=1 can clamp) -> 3 precomputed qB pointers (one per kw).
#define DO_PHASE(I, F0v, F1v, F2v, F3v) do {                                          \
    const int kh_ = (((I) % 18) >> 1) / 3, kw_ = (((I) % 18) >> 1) % 3;               \
    const int cio_ = ((I) / 18) * 64 + ((I) & 1) * 32;                                \
    const bf16_t* b0_ = pB + (size_t)(kh_ * CDIM + kw_) * LSTR + cio_;                \
    const bf16_t* q_  = (kw_ == 0) ? qB0 : ((kw_ == 1) ? qB1 : qB2);                  \
    bf16x8 m0_ = *(const bf16x8*)(b0_);                                               \
    bf16x8 m1_ = *(const bf16x8*)(q_ + (size_t)(kh_ * CDIM) * LSTR + cio_);           \
    __builtin_amdgcn_s_setprio(1);                                                    \
    acc[0][0] = __builtin_amdgcn_mfma_f32_16x16x32_bf16(F0v, m0_, acc[0][0], 0,0,0);  \
    acc[1][0] = __builtin_amdgcn_mfma_f32_16x16x32_bf16(F1v, m0_, acc[1][0], 0,0,0);  \
    acc[2][0] = __builtin_amdgcn_mfma_f32_16x16x32_bf16(F2v, m0_, acc[2][0], 0,0,0);  \
    acc[3][0] = __builtin_amdgcn_mfma_f32_16x16x32_bf16(F3v, m0_, acc[3][0], 0,0,0);  \
    acc[0][1] = __builtin_amdgcn_mfma_f32_16x16x32_bf16(F0v, m1_, acc[0][1], 0,0,0);  \
    acc[1][1] = __builtin_amdgcn_mfma_f32_16x16x32_bf16(F1v, m1_, acc[1][1], 0,0,0);  \
    acc[2][1] = __builtin_amdgcn_mfma_f32_16x16x32_bf16(F2v, m1_, acc[2][1], 0,0,0);  \
    acc[3][1] = __builtin_amdgcn_mfma_f32_16x16x32_bf16(F3v, m1_, acc[3][1], 0,0,0);  \
    __builtin_amdgcn_s_setprio(0);                                                    \
} while (0)

#define PREFETCH(I, F0v, F1v, F2v, F3v) do {                                          \
    const bf16_t* wp_ = wpbase + FRAG_OFF(I);                                         \
    F0v = *(const bf16x8*)(wp_);                                                      \
    F1v = *(const bf16x8*)(wp_ + 512);                                                \
    F2v = *(const bf16x8*)(wp_ + 1024);                                               \
    F3v = *(const bf16x8*)(wp_ + 1536);                                               \
} while (0)

// sync staging, all 4 slabs: unit G = cig*232 + rr*58 + c (3712 units)
#define STAGE_UNIT(G) do {                                                            \
    int G_ = (G);                                                                     \
    int cig = G_ / 232, rem = G_ - cig * 232;                                         \
    int rr  = rem / 58, c  = rem - rr * 58;                                           \
    int r_in = h0 - 1 + rr, w = c - 1;                                                \
    uint32_t u[8];                                                                    \
    if (r_in >= 0 && r_in < HH && w >= 0 && w < WW) {                                 \
        const float* src = in + (((size_t)n * CIN + cig * 8) * HH + r_in) * WW + w;   \
        float v[8];                                                                   \
        _Pragma("unroll")                                                             \
        for (int j = 0; j < 8; ++j) v[j] = src[(size_t)j * HW];                       \
        _Pragma("unroll")                                                             \
        for (int j = 0; j < 8; ++j) { bf16_t b = (bf16_t)v[j]; u[j] = *(const uint16_t*)&b; } \
    } else {                                                                          \
        _Pragma("unroll")                                                             \
        for (int j = 0; j < 8; ++j) u[j] = 0;                                         \
    }                                                                                 \
    uint4 o;                                                                          \
    o.x = u[0] | (u[1] << 16); o.y = u[2] | (u[3] << 16);                             \
    o.z = u[4] | (u[5] << 16); o.w = u[6] | (u[7] << 16);                             \
    *(uint4*)&inp[(rr * CDIM + c) * LSTR + cig * 8] = o;                              \
} while (0)

__global__ __launch_bounds__(512) __attribute__((amdgpu_waves_per_eu(4, 4)))
void conv_fused_kernel(const float* __restrict__ in, const bf16_t* __restrict__ Wt2,
                       const float* __restrict__ bias, float* __restrict__ out) {
    __shared__ __align__(16) unsigned char smem[4 * CDIM * 272];   // 63,104 B: 4 slabs
    bf16_t* inp = (bf16_t*)smem;

    // XCD swizzle: 448 = 8 x 56 -> each XCD gets 2 whole images.
    const int bx0 = blockIdx.x;
    const int bx  = (bx0 & 7) * 56 + (bx0 >> 3);
    const int n   = bx / ROWPAIRS;
    const int h0  = (bx % ROWPAIRS) * 2;         // output rows h0,h0+1; slabs rows h0-1..h0+2

    const int tid  = threadIdx.x;
    const int lane = tid & 63;
    const int wave = tid >> 6;                   // 0..7
    const int ws  = wave & 1;                    // output row within pair
    const int wc  = (wave >> 1) & 1;             // co half (64)
    const int tsh = wave >> 2;                   // col half (32)
    const int l15 = lane & 15;
    const int l4  = lane >> 4;

    // ---- stage all 4 slabs synchronously: 3712 units
#pragma unroll
    for (int it = 0; it < 7; ++it) STAGE_UNIT(it * 512 + tid);
    if (tid < 128) STAGE_UNIT(3584 + tid);
    __syncthreads();

    f32x4 acc[4][2];                             // [tc][tsl] -> 32 regs
#pragma unroll
    for (int a = 0; a < 4; ++a)
#pragma unroll
        for (int b2 = 0; b2 < 2; ++b2) acc[a][b2] = (f32x4){0.f, 0.f, 0.f, 0.f};

    // LDS bases: m0 at col tsh*32+l15 (+kw per phase); m1 via qB[kw] (clamped)
    const bf16_t* pB = inp + (size_t)(ws * CDIM + tsh * 32 + l15) * LSTR + l4 * 8;
    int cq0 = tsh * 32 + 16 + l15;     if (cq0 > 57) cq0 = 57;
    int cq1 = tsh * 32 + 16 + l15 + 1; if (cq1 > 57) cq1 = 57;
    int cq2 = tsh * 32 + 16 + l15 + 2; if (cq2 > 57) cq2 = 57;
    const bf16_t* qB0 = inp + (size_t)(ws * CDIM + cq0) * LSTR + l4 * 8;
    const bf16_t* qB1 = inp + (size_t)(ws * CDIM + cq1) * LSTR + l4 * 8;
    const bf16_t* qB2 = inp + (size_t)(ws * CDIM + cq2) * LSTR + l4 * 8;

    // weight fragment base: rec = (khkw*4 + chunk)*8 + wc*4 + tc (tc contiguous)
    const bf16_t* wpbase = Wt2 + (size_t)(wc * 4) * 512 + (size_t)lane * 8;

    bf16x8 A0, A1, A2, A3, B0, B1, B2, B3;       // 4 frags/phase, prefetch distance 2
    PREFETCH(0, A0, A1, A2, A3);
    PREFETCH(1, B0, B1, B2, B3);

#pragma unroll
    for (int ii = 0; ii < 17; ++ii) {
        const int i0 = ii * 2;
        DO_PHASE(i0, A0, A1, A2, A3);
        PREFETCH(i0 + 2, A0, A1, A2, A3);
        DO_PHASE(i0 + 1, B0, B1, B2, B3);
        PREFETCH(i0 + 3, B0, B1, B2, B3);
    }
    DO_PHASE(34, A0, A1, A2, A3);
    DO_PHASE(35, B0, B1, B2, B3);

    // ---- epilogue: direct store; wave owns 1 row x 64 co x 32 cols
    {
        const int h = h0 + ws;
        float* obase = out + ((size_t)n * COUT) * HW + (size_t)h * WW;
#pragma unroll
        for (int tc = 0; tc < 4; ++tc) {
#pragma unroll
            for (int tsl = 0; tsl < 2; ++tsl) {
                f32x4 r = acc[tc][tsl];
                int w0 = tsh * 32 + tsl * 16 + l15;
                if (w0 < WW) {
#pragma unroll
                    for (int i = 0; i < 4; ++i) {
                        int co = wc * 64 + tc * 16 + l4 * 4 + i;
                        obase[(size_t)co * HW + w0] = r[i] + bias[co];
                    }
                }
            }
        }
    }
}

extern "C" void kernel_launch(void* const* d_in, const int* in_sizes, int n_in,
                              void* d_out, int out_size, void* d_ws, size_t ws_size,
                              hipStream_t stream) {
    const float* in   = (const float*)d_in[0];
    const float* wgt  = (const float*)d_in[1];
    const float* bias = (const float*)d_in[2];
    float* out = (float*)d_out;

    bf16_t* Wt2 = (bf16_t*)d_ws;                 // 294,912 B, fragment-major

    wtrans_kernel<<<72, 256, 0, stream>>>(wgt, Wt2);
    conv_fused_kernel<<<NBLK, 512, 0, stream>>>(in, Wt2, bias, out);
}

// Round 16
// 100.785 us; speedup vs baseline: 1.0172x; 1.0172x over previous
//
#include <hip/hip_runtime.h>
#include <stdint.h>
#include <stddef.h>

typedef __bf16 bf16_t;
typedef __bf16 bf16x8 __attribute__((ext_vector_type(8)));
typedef float  f32x4  __attribute__((ext_vector_type(4)));

#define NIMG 16
#define CIN  128
#define COUT 128
#define HH   56
#define WW   56
#define HW   (HH * WW)       // 3136
#define CDIM 58              // staged c extent: c = w+1, w = -1..56
#define LSTR 136             // LDS c-stride in bf16: 272B record
#define ROWPAIRS 28
#define NBLK (NIMG * ROWPAIRS)   // 448 blocks, 2 output rows each

// R16 = R8 (best, 95.4) + ONE variable: nontemporal output stores. Mechanism: the
// 25.7MB output stream allocates in L2 and evicts the resident weight tensor
// (288KB, re-read by every block) and the input halo rows (the XCD swizzle's L2
// locality), explaining R6's measured ~53MB/round input fetch (no halo reuse).
// nt stores keep the output out of L2's way.
// R15 lesson (ledger): re-partitioning trades LDS bytes vs weight bytes at a
// constant product; escaping needs 32x32 MFMA or 64-reg acc (spill cliff).

// ---------- prologue: W[co][ci][3][3] fp32 -> Wt2 fragment-major bf16 ----------
// 288 recs * 64 lanes = 18432 threads = EXACTLY 72 blocks (overrun raced in R2/R3).
__global__ void wtrans_kernel(const float* __restrict__ w, bf16_t* __restrict__ wt2) {
    int t = blockIdx.x * 256 + threadIdx.x;
    int lane = t & 63, rec = t >> 6;              // rec 0..287
    int l15 = lane & 15, l4 = lane >> 4;
    int cotile = rec & 7, chunk = (rec >> 3) & 3, khkw = rec >> 5;
    int co  = cotile * 16 + l15;
    int ci0 = chunk * 32 + l4 * 8;
    const float* src = w + ((size_t)co * CIN + ci0) * 9 + khkw;
    bf16x8 o;
#pragma unroll
    for (int j = 0; j < 8; ++j) o[j] = (bf16_t)src[(size_t)j * 9];
    *(bf16x8*)(wt2 + (size_t)rec * 512 + (size_t)lane * 8) = o;
}

// ---------- fused conv: block = (n, 2 rows) x 128 co; 512 thr = 8 waves ----------
// wave = wc*2 + ws: ws = output row within pair, wc = cout quarter (32).
// 36 phases: I in [0,36), half = I/18, j = I%18, khkw = j>>1, cs = j&1,
// chunk = half*2 + cs, kh = khkw/3, kw = khkw%3. 8 MFMA/phase (tc 0..1 x ts 0..3).
#define FRAG_OFF(I) ((size_t)((((((I) % 18) >> 1) * 4 + (((I) / 18) * 2 + ((I) & 1))) * 8)) * 512)

// All LDS B addresses = per-lane base + compile-time byte immediate; only ts=3 can
// clamp (ts<=2 max col = 49 <= 57) -> 3 precomputed clamped bases per kw.
#define DO_PHASE(I, F0v, F1v) do {                                                    \
    const int kh_ = (((I) % 18) >> 1) / 3, kw_ = (((I) % 18) >> 1) % 3;               \
    const int cio_ = ((I) / 18) * 64 + ((I) & 1) * 32;                                \
    const bf16_t* b0_ = pB + (size_t)(kh_ * CDIM + kw_) * LSTR + cio_;                \
    const bf16_t* pb3_ = (kw_ == 0) ? pB3_0 : ((kw_ == 1) ? pB3_1 : pB3_2);           \
    const bf16_t* b3_ = pb3_ + (size_t)(kh_ * CDIM) * LSTR + cio_;                    \
    bf16x8 m0_ = *(const bf16x8*)(b0_);                                               \
    bf16x8 m1_ = *(const bf16x8*)(b0_ + 16 * LSTR);                                   \
    bf16x8 m2_ = *(const bf16x8*)(b0_ + 32 * LSTR);                                   \
    bf16x8 m3_ = *(const bf16x8*)(b3_);                                               \
    __builtin_amdgcn_s_setprio(1);                                                    \
    acc[0][0] = __builtin_amdgcn_mfma_f32_16x16x32_bf16(F0v, m0_, acc[0][0], 0,0,0);  \
    acc[1][0] = __builtin_amdgcn_mfma_f32_16x16x32_bf16(F1v, m0_, acc[1][0], 0,0,0);  \
    acc[0][1] = __builtin_amdgcn_mfma_f32_16x16x32_bf16(F0v, m1_, acc[0][1], 0,0,0);  \
    acc[1][1] = __builtin_amdgcn_mfma_f32_16x16x32_bf16(F1v, m1_, acc[1][1], 0,0,0);  \
    acc[0][2] = __builtin_amdgcn_mfma_f32_16x16x32_bf16(F0v, m2_, acc[0][2], 0,0,0);  \
    acc[1][2] = __builtin_amdgcn_mfma_f32_16x16x32_bf16(F1v, m2_, acc[1][2], 0,0,0);  \
    acc[0][3] = __builtin_amdgcn_mfma_f32_16x16x32_bf16(F0v, m3_, acc[0][3], 0,0,0);  \
    acc[1][3] = __builtin_amdgcn_mfma_f32_16x16x32_bf16(F1v, m3_, acc[1][3], 0,0,0);  \
    __builtin_amdgcn_s_setprio(0);                                                    \
} while (0)

#define PREFETCH(I, F0v, F1v) do {                                                    \
    const bf16_t* wp_ = wpbase + FRAG_OFF(I);                                         \
    F0v = *(const bf16x8*)(wp_);                                                      \
    F1v = *(const bf16x8*)(wp_ + 512);                                                \
} while (0)

// staging: unit G = cig*232 + rr*58 + c (c fastest -> contiguous walk)
#define STAGE_UNIT(G) do {                                                            \
    int G_ = (G);                                                                     \
    int cig = G_ / 232, rem = G_ - cig * 232;                                         \
    int rr  = rem / 58, c  = rem - rr * 58;                                           \
    int r_in = h0 - 1 + rr, w = c - 1;                                                \
    uint32_t u[8];                                                                    \
    if (r_in >= 0 && r_in < HH && w >= 0 && w < WW) {                                 \
        const float* src = in + (((size_t)n * CIN + cig * 8) * HH + r_in) * WW + w;   \
        float v[8];                                                                   \
        _Pragma("unroll")                                                             \
        for (int j = 0; j < 8; ++j) v[j] = src[(size_t)j * HW];                       \
        _Pragma("unroll")                                                             \
        for (int j = 0; j < 8; ++j) { bf16_t b = (bf16_t)v[j]; u[j] = *(const uint16_t*)&b; } \
    } else {                                                                          \
        _Pragma("unroll")                                                             \
        for (int j = 0; j < 8; ++j) u[j] = 0;                                         \
    }                                                                                 \
    uint4 o;                                                                          \
    o.x = u[0] | (u[1] << 16); o.y = u[2] | (u[3] << 16);                             \
    o.z = u[4] | (u[5] << 16); o.w = u[6] | (u[7] << 16);                             \
    *(uint4*)&inp[(rr * CDIM + c) * LSTR + cig * 8] = o;                              \
} while (0)

__global__ __launch_bounds__(512) __attribute__((amdgpu_waves_per_eu(4, 4)))
void conv_fused_kernel(const float* __restrict__ in, const bf16_t* __restrict__ Wt2,
                       const float* __restrict__ bias, float* __restrict__ out) {
    __shared__ __align__(16) unsigned char smem[63104];   // input stage only
    bf16_t* inp = (bf16_t*)smem;

    // XCD swizzle: 448 = 8 x 56 -> each XCD gets 2 whole images (halo rows L2-hit,
    // provided the output stream doesn't evict them -> nt stores below).
    const int bx0 = blockIdx.x;
    const int bx  = (bx0 & 7) * 56 + (bx0 >> 3);

    const int n  = bx / ROWPAIRS;
    const int h0 = (bx % ROWPAIRS) * 2;          // output rows h0,h0+1; input rows h0-1..h0+2

    const int tid  = threadIdx.x;
    const int lane = tid & 63;
    const int wave = tid >> 6;                   // 0..7
    const int ws  = wave & 1;                    // output row within pair
    const int wc  = wave >> 1;                   // cout quarter (32 co)
    const int l15 = lane & 15;
    const int l4  = lane >> 4;

    // ---- stage HALF0 (ci 0..63): units 0..1855
#pragma unroll
    for (int it = 0; it < 3; ++it) STAGE_UNIT(it * 512 + tid);
    if (tid < 320) STAGE_UNIT(1536 + tid);
    __syncthreads();                             // half0 ready; MFMA on ci<64 can start

    // ---- stage HALF1 (ci 64..127): units 1856..3711 (record bytes 128..255, disjoint)
#pragma unroll
    for (int it = 0; it < 3; ++it) STAGE_UNIT(1856 + it * 512 + tid);
    if (tid < 320) STAGE_UNIT(3392 + tid);

    f32x4 acc[2][4];                             // [tc][ts] -> 32 regs
#pragma unroll
    for (int a = 0; a < 2; ++a)
#pragma unroll
        for (int b2 = 0; b2 < 4; ++b2) acc[a][b2] = (f32x4){0.f, 0.f, 0.f, 0.f};

    // bias preload (8 values this thread will need; L2-hot after first block)
    float bco[8];
#pragma unroll
    for (int tc = 0; tc < 2; ++tc)
#pragma unroll
        for (int i = 0; i < 4; ++i) bco[tc * 4 + i] = bias[wc * 32 + tc * 16 + l4 * 4 + i];

    // LDS B bases (ws, lane folded in; all phase offsets are compile-time imms)
    const bf16_t* pB = inp + (size_t)(ws * CDIM + l15) * LSTR + l4 * 8;
    int c3_0 = 48 + l15;     if (c3_0 > 57) c3_0 = 57;    // ts=3 clamped cols per kw
    int c3_1 = 48 + l15 + 1; if (c3_1 > 57) c3_1 = 57;
    int c3_2 = 48 + l15 + 2; if (c3_2 > 57) c3_2 = 57;
    const bf16_t* pB3_0 = inp + (size_t)(ws * CDIM + c3_0) * LSTR + l4 * 8;
    const bf16_t* pB3_1 = inp + (size_t)(ws * CDIM + c3_1) * LSTR + l4 * 8;
    const bf16_t* pB3_2 = inp + (size_t)(ws * CDIM + c3_2) * LSTR + l4 * 8;

    // weight fragment base: rec = (khkw*4 + chunk)*8 + wc*2 + tc
    const bf16_t* wpbase = Wt2 + (size_t)(wc * 2) * 512 + (size_t)lane * 8;

    bf16x8 A0, A1, B0, B1;                       // 2 frags/phase, prefetch distance 2
    PREFETCH(0, A0, A1);
    PREFETCH(1, B0, B1);

    // ---- K half 0: phases 0..17 (ci < 64)
#pragma unroll
    for (int ii = 0; ii < 8; ++ii) {
        const int i0 = ii * 2;
        DO_PHASE(i0, A0, A1);
        PREFETCH(i0 + 2, A0, A1);
        DO_PHASE(i0 + 1, B0, B1);
        PREFETCH(i0 + 3, B0, B1);
    }
    DO_PHASE(16, A0, A1);
    PREFETCH(18, A0, A1);
    DO_PHASE(17, B0, B1);
    PREFETCH(19, B0, B1);

    __syncthreads();                             // half1 LDS writes complete

    // ---- K half 1: phases 18..35 (ci >= 64)
#pragma unroll
    for (int ii = 9; ii < 17; ++ii) {
        const int i0 = ii * 2;
        DO_PHASE(i0, A0, A1);
        PREFETCH(i0 + 2, A0, A1);
        DO_PHASE(i0 + 1, B0, B1);
        PREFETCH(i0 + 3, B0, B1);
    }
    DO_PHASE(34, A0, A1);
    DO_PHASE(35, B0, B1);

    // ---- epilogue: direct NONTEMPORAL stores (keep output out of L2 so weights
    // and input halo stay resident — the round's single experimental variable)
    {
        const int h = h0 + ws;
        float* obase = out + ((size_t)n * COUT) * HW + (size_t)h * WW;
#pragma unroll
        for (int tc = 0; tc < 2; ++tc) {
#pragma unroll
            for (int ts = 0; ts < 4; ++ts) {
                f32x4 r = acc[tc][ts];
                int w0 = ts * 16 + l15;
                if (w0 < WW) {
#pragma unroll
                    for (int i = 0; i < 4; ++i) {
                        int co = wc * 32 + tc * 16 + l4 * 4 + i;
                        __builtin_nontemporal_store(r[i] + bco[tc * 4 + i],
                                                    &obase[(size_t)co * HW + w0]);
                    }
                }
            }
        }
    }
}

extern "C" void kernel_launch(void* const* d_in, const int* in_sizes, int n_in,
                              void* d_out, int out_size, void* d_ws, size_t ws_size,
                              hipStream_t stream) {
    const float* in   = (const float*)d_in[0];
    const float* wgt  = (const float*)d_in[1];
    const float* bias = (const float*)d_in[2];
    float* out = (float*)d_out;

    bf16_t* Wt2 = (bf16_t*)d_ws;                 // 294,912 B, fragment-major

    wtrans_kernel<<<72, 256, 0, stream>>>(wgt, Wt2);
    conv_fused_kernel<<<NBLK, 512, 0, stream>>>(in, Wt2, bias, out);
}